// Round 7
// baseline (432.360 us; speedup 1.0000x reference)
//
#include <hip/hip_runtime.h>
#include <math.h>

constexpr int LI = 8192;   // I (intermediate)
constexpr int LD = 2048;   // D (hidden)
constexpr int LN = 2048;   // N (tokens)
constexpr int LK = 32;     // top_k
constexpr int CAP = 192;   // candidate band cap per row

typedef short short8 __attribute__((ext_vector_type(8)));
typedef float f32x4 __attribute__((ext_vector_type(4)));
typedef const __attribute__((address_space(1))) void* gas1_t;
typedef __attribute__((address_space(3))) void* las3_t;

__device__ __forceinline__ void gload16(const void* g, void* l) {
    __builtin_amdgcn_global_load_lds((gas1_t)g, (las3_t)l, 16, 0, 0);
}

// ---- fp32 -> bf16 (RNE), layer-indirected source
__global__ __launch_bounds__(256) void k_cvt_h(
    const float* __restrict__ src, const int* __restrict__ layer_idx,
    size_t lstride, unsigned short* __restrict__ hi, int n4)
{
    const float* __restrict__ s = src + (size_t)layer_idx[0] * lstride;
    int i = blockIdx.x * 256 + threadIdx.x;
    int stride = gridDim.x * 256;
    for (; i < n4; i += stride) {
        float4 v = ((const float4*)s)[i];
        float f[4] = {v.x, v.y, v.z, v.w};
        unsigned short hh[4];
        #pragma unroll
        for (int j = 0; j < 4; ++j) {
            unsigned u = __float_as_uint(f[j]);
            hh[j] = (unsigned short)((u + 0x7fffu + ((u >> 16) & 1u)) >> 16);
        }
        ushort4 h = {hh[0], hh[1], hh[2], hh[3]};
        ((ushort4*)hi)[i] = h;
    }
}

// ---- zk = bf16(|silu(x @ gw^T)|) via single bf16 MFMA, 128x128 tile, BK=64.
// Structure verified in round 4 (passed); lo-terms removed, key epilogue added.
__global__ __launch_bounds__(256) void k_gemm_z(
    const unsigned short* __restrict__ xh, const unsigned short* __restrict__ wh,
    unsigned short* __restrict__ zk)
{
    __shared__ short lds[16384];   // Ah|Bh, each [128][64] bf16 = 16KB
    short* Ah = lds;
    short* Bh = lds + 8192;

    const int tid = threadIdx.x;
    const int w = tid >> 6, lane = tid & 63;
    const int bn = blockIdx.y * 128;   // token rows
    const int bi = blockIdx.x * 128;   // neuron rows

    const int srow   = w * 32 + (lane >> 3);
    const int schunk = (lane & 7) ^ ((lane >> 3) & 7);   // inverse-swizzled source
    const unsigned short* xbh = xh + (size_t)(bn + srow) * LD + schunk * 8;
    const unsigned short* wbh = wh + (size_t)(bi + srow) * LD + schunk * 8;

    f32x4 acc[4][4];
    #pragma unroll
    for (int m = 0; m < 4; ++m)
        #pragma unroll
        for (int n = 0; n < 4; ++n) acc[m][n] = (f32x4){0.f, 0.f, 0.f, 0.f};

    const int wm = (w >> 1) * 64, wn = (w & 1) * 64;

    #define STAGE(k0)                                                          \
        {                                                                      \
            _Pragma("unroll")                                                  \
            for (int t = 0; t < 4; ++t) {                                      \
                int ldo = (w * 32 + t * 8) * 64;                               \
                size_t go = (size_t)t * 8 * LD + (k0);                         \
                gload16(xbh + go, Ah + ldo);                                   \
                gload16(wbh + go, Bh + ldo);                                   \
            }                                                                  \
        }

    STAGE(0);
    __syncthreads();
    for (int k0 = 0;;) {
        #pragma unroll
        for (int ks = 0; ks < 2; ++ks) {
            short8 a_h[4], b_h[4];
            #pragma unroll
            for (int m = 0; m < 4; ++m) {
                int lr = wm + m * 16 + (lane & 15);
                int lc = ks * 4 + (lane >> 4);
                a_h[m] = *(const short8*)(Ah + lr * 64 + ((lc ^ (lr & 7)) << 3));
            }
            #pragma unroll
            for (int n = 0; n < 4; ++n) {
                int lr = wn + n * 16 + (lane & 15);
                int lc = ks * 4 + (lane >> 4);
                b_h[n] = *(const short8*)(Bh + lr * 64 + ((lc ^ (lr & 7)) << 3));
            }
            #pragma unroll
            for (int m = 0; m < 4; ++m)
                #pragma unroll
                for (int n = 0; n < 4; ++n)
                    acc[m][n] = __builtin_amdgcn_mfma_f32_16x16x32_bf16(a_h[m], b_h[n], acc[m][n], 0, 0, 0);
        }
        k0 += 64;
        if (k0 >= LD) break;
        __syncthreads();
        STAGE(k0);
        __syncthreads();
    }

    // epilogue: key = bf16(|silu(z)|); C/D layout col=lane&15, row=(lane>>4)*4+r
    #pragma unroll
    for (int m = 0; m < 4; ++m) {
        int rb = bn + wm + m * 16 + (lane >> 4) * 4;
        #pragma unroll
        for (int n = 0; n < 4; ++n) {
            int cb = bi + wn + n * 16 + (lane & 15);
            #pragma unroll
            for (int r = 0; r < 4; ++r) {
                float zv = acc[m][n][r];
                float g = zv / (1.f + expf(-zv));
                unsigned u = __float_as_uint(fabsf(g));
                zk[(size_t)(rb + r) * LI + cb] =
                    (unsigned short)((u + 0x7fffu + ((u >> 16) & 1u)) >> 16);
            }
        }
    }
    #undef STAGE
}

// ---- per-row band selection: 4096-bin histogram on bf16 key bits, threshold
// bin covering rank-32, collect keys >= binfloor - MARGIN (superset of top-32).
__global__ __launch_bounds__(256) void k_select(
    const unsigned short* __restrict__ zk, int* __restrict__ band,
    int* __restrict__ bandcnt, int* __restrict__ ghist)
{
    __shared__ int hist[4096];   // 16 KB
    __shared__ int sums[256];
    __shared__ int red[4];
    __shared__ int base_s;
    __shared__ int thrbin_s;

    const int row = blockIdx.x;
    const int tid = threadIdx.x;
    const int lane = tid & 63, w = tid >> 6;
    const unsigned short* __restrict__ z = zk + (size_t)row * LI;

    if (tid == 0) thrbin_s = 0;
    for (int i = tid; i < 4096; i += 256) hist[i] = 0;
    __syncthreads();
    for (int i = tid; i < LI; i += 256)
        atomicAdd(&hist[z[i] >> 3], 1);   // sign=0: uint order == value order
    __syncthreads();

    int own = 0;
    #pragma unroll
    for (int b = 0; b < 16; ++b) own += hist[tid * 16 + b];
    sums[tid] = own;
    __syncthreads();
    // suffix inclusive scan: sums[t] = sum_{u>=t} own_u
    for (int st = 1; st < 256; st <<= 1) {
        int v = (tid + st < 256) ? sums[tid + st] : 0;
        __syncthreads();
        sums[tid] += v;
        __syncthreads();
    }
    int after = (tid < 255) ? sums[tid + 1] : 0;   // strictly above my 16 bins
    if (after < LK && after + own >= LK) {          // unique crossing thread
        int cum = after;
        for (int b = 15; b >= 0; --b) {
            cum += hist[tid * 16 + b];
            if (cum >= LK) { thrbin_s = tid * 16 + b; break; }
        }
    }
    __syncthreads();
    const float bandlo =
        __uint_as_float(((unsigned)(thrbin_s << 3)) << 16) - 0.1f;  // covers 2E

    // ordered candidate collection (ascending index), cap CAP
    if (tid == 0) base_s = 0;
    __syncthreads();
    for (int c0 = 0; c0 < LI; c0 += 256) {
        float kf = __uint_as_float(((unsigned)z[c0 + tid]) << 16);
        bool f = kf >= bandlo;
        unsigned long long m = __ballot(f);
        if (lane == 0) red[w] = __popcll(m);
        __syncthreads();
        int wbase = base_s;
        for (int ww = 0; ww < w; ++ww) wbase += red[ww];
        int pos = wbase + __popcll(m & ((1ull << lane) - 1ull));
        if (f && pos < CAP) {
            band[row * CAP + pos] = c0 + tid;
            atomicAdd(&ghist[c0 + tid], 1);
        }
        __syncthreads();
        if (tid == 0) base_s += red[0] + red[1] + red[2] + red[3];
        __syncthreads();
    }
    if (tid == 0) bandcnt[row] = base_s < CAP ? base_s : CAP;
}

// ---- exclusive prefix-sum of ghist[8192] -> offs, cursor (single block)
__global__ __launch_bounds__(256) void k_scan(
    const int* __restrict__ ghist, int* __restrict__ offs, int* __restrict__ cursor)
{
    __shared__ int sums[256];
    const int tid = threadIdx.x;
    int loc[32];
    int s = 0;
    #pragma unroll
    for (int b = 0; b < 32; ++b) { loc[b] = s; s += ghist[tid * 32 + b]; }
    sums[tid] = s;
    __syncthreads();
    for (int st = 1; st < 256; st <<= 1) {
        int v = (tid >= st) ? sums[tid - st] : 0;
        __syncthreads();
        sums[tid] += v;
        __syncthreads();
    }
    int base = (tid > 0) ? sums[tid - 1] : 0;
    #pragma unroll
    for (int b = 0; b < 32; ++b) {
        int o = base + loc[b];
        offs[tid * 32 + b]   = o;
        cursor[tid * 32 + b] = o;
    }
}

// ---- scatter band entries into neuron-major inverted list
__global__ __launch_bounds__(256) void k_scatter(
    const int* __restrict__ band, const int* __restrict__ bandcnt,
    int* __restrict__ cursor, int* __restrict__ inv)
{
    const int row = blockIdx.x;
    const int tid = threadIdx.x;
    int cnt = bandcnt[row];
    if (tid < cnt) {
        int j = band[row * CAP + tid] & (LI - 1);
        int p = atomicAdd(&cursor[j], 1);
        inv[p] = (row << 8) | tid;
    }
}

// ---- neuron-major exact rescore: stream gate[j],up[j] once (fp32), gather x
__global__ __launch_bounds__(256) void k_pair(
    const float* __restrict__ x, const float* __restrict__ gate,
    const float* __restrict__ up, const int* __restrict__ layer_idx,
    const int* __restrict__ ghist, const int* __restrict__ offs,
    const int* __restrict__ inv,
    float* __restrict__ gdot, float* __restrict__ udot)
{
    __shared__ float gs[LD];   // 8 KB
    __shared__ float us[LD];   // 8 KB
    const int j = blockIdx.x;
    const int tid = threadIdx.x;
    const int lane = tid & 63, w = tid >> 6;
    const int nj = ghist[j];
    if (nj == 0) return;
    const float* __restrict__ gr = gate + (size_t)layer_idx[0] * LI * LD + (size_t)j * LD;
    const float* __restrict__ ur = up   + (size_t)layer_idx[0] * LI * LD + (size_t)j * LD;
    for (int i = tid * 4; i < LD; i += 1024) {
        *(float4*)&gs[i] = *(const float4*)(gr + i);
        *(float4*)&us[i] = *(const float4*)(ur + i);
    }
    __syncthreads();
    const int base = offs[j];
    for (int e = w; e < nj; e += 4) {
        int packed = inv[base + e];
        int row = packed >> 8, slot = packed & 255;
        const float* __restrict__ xr = x + (size_t)row * LD;
        float gd = 0.f, ud = 0.f;
        for (int i = lane * 4; i < LD; i += 256) {
            float4 xv = *(const float4*)(xr + i);
            gd = fmaf(xv.x, gs[i+0], gd); gd = fmaf(xv.y, gs[i+1], gd);
            gd = fmaf(xv.z, gs[i+2], gd); gd = fmaf(xv.w, gs[i+3], gd);
            ud = fmaf(xv.x, us[i+0], ud); ud = fmaf(xv.y, us[i+1], ud);
            ud = fmaf(xv.z, us[i+2], ud); ud = fmaf(xv.w, us[i+3], ud);
        }
        #pragma unroll
        for (int o = 32; o; o >>= 1) {
            gd += __shfl_down(gd, o);
            ud += __shfl_down(ud, o);
        }
        if (lane == 0) {
            gdot[(size_t)row * CAP + slot] = gd;
            udot[(size_t)row * CAP + slot] = ud;
        }
    }
}

// ---- per-row exact top-32 among band (desc exact key, asc idx); gu = silu*u
__global__ __launch_bounds__(256) void k_final(
    const int* __restrict__ band, const int* __restrict__ bandcnt,
    const float* __restrict__ gdot, const float* __restrict__ udot,
    int* __restrict__ idx_out, float* __restrict__ gu_out)
{
    __shared__ float ckey[CAP];
    __shared__ float cgu[CAP];
    __shared__ int   cidx[CAP];
    const int row = blockIdx.x;
    const int tid = threadIdx.x;
    const int lane = tid & 63;
    const int cnt = bandcnt[row];
    if (tid < CAP) { ckey[tid] = -1.f; cgu[tid] = 0.f; cidx[tid] = 0x7fffffff; }
    __syncthreads();
    if (tid < cnt) {
        float gd = gdot[(size_t)row * CAP + tid];
        float g = gd / (1.f + expf(-gd));
        ckey[tid] = fabsf(g);
        cgu[tid]  = g * udot[(size_t)row * CAP + tid];
        cidx[tid] = band[row * CAP + tid];
    }
    __syncthreads();
    if (tid < 64) {
        float k1 = ckey[lane], k2 = ckey[lane + 64], k3 = ckey[lane + 128];
        int   i1 = cidx[lane], i2 = cidx[lane + 64], i3 = cidx[lane + 128];
        int   p1 = lane, p2 = lane + 64, p3 = lane + 128;
        for (int slot = 0; slot < LK; ++slot) {
            float bk = k1; int bi_ = i1, bp = p1;
            if (k2 > bk || (k2 == bk && i2 < bi_)) { bk = k2; bi_ = i2; bp = p2; }
            if (k3 > bk || (k3 == bk && i3 < bi_)) { bk = k3; bi_ = i3; bp = p3; }
            #pragma unroll
            for (int o = 1; o < 64; o <<= 1) {
                float ok = __shfl_xor(bk, o);
                int  oi = __shfl_xor(bi_, o);
                int  op = __shfl_xor(bp, o);
                if (ok > bk || (ok == bk && oi < bi_)) { bk = ok; bi_ = oi; bp = op; }
            }
            if (lane == 0) {
                idx_out[row * LK + slot] = bi_ & (LI - 1);
                gu_out[row * LK + slot]  = cgu[bp < CAP ? bp : 0];
            }
            if (p1 == bp) { k1 = -1.f; i1 = 0x7fffffff; }
            if (p2 == bp) { k2 = -1.f; i2 = 0x7fffffff; }
            if (p3 == bp) { k3 = -1.f; i3 = 0x7fffffff; }
        }
    }
}

// ---- transpose down[D,I] -> dT[I,D]
__global__ __launch_bounds__(256) void k_transpose(
    const float* __restrict__ down, const int* __restrict__ layer_idx,
    float* __restrict__ dT)
{
    const float* __restrict__ dw = down + (size_t)layer_idx[0] * LD * LI;
    __shared__ float t[32][33];
    const int bi = blockIdx.x * 32;
    const int bd = blockIdx.y * 32;
    const int tx = threadIdx.x & 31, ty = threadIdx.x >> 5;
    #pragma unroll
    for (int r = ty; r < 32; r += 8)
        t[r][tx] = dw[(size_t)(bd + r) * LI + bi + tx];
    __syncthreads();
    #pragma unroll
    for (int r = ty; r < 32; r += 8)
        dT[(size_t)(bi + r) * LD + bd + tx] = t[tx][r];
}

// ---- out[n,:] = sum_k gu[n,k] * dT[idx[n,k], :]
__global__ __launch_bounds__(256) void k_down(
    const float* __restrict__ dT, const int* __restrict__ idx,
    const float* __restrict__ gu, float* __restrict__ out)
{
    __shared__ int   js[LK];
    __shared__ float wgt[LK];
    const int row = blockIdx.x;
    const int tid = threadIdx.x;
    if (tid < LK) {
        js[tid]  = idx[row * LK + tid] & (LI - 1);
        wgt[tid] = gu[row * LK + tid];
    }
    __syncthreads();
    float4 a0 = {0.f,0.f,0.f,0.f}, a1 = {0.f,0.f,0.f,0.f};
    #pragma unroll 4
    for (int k = 0; k < LK; ++k) {
        const float* __restrict__ dr = dT + (size_t)js[k] * LD;
        float wv = wgt[k];
        float4 v0 = *(const float4*)(dr + tid * 4);
        float4 v1 = *(const float4*)(dr + 1024 + tid * 4);
        a0.x = fmaf(wv, v0.x, a0.x); a0.y = fmaf(wv, v0.y, a0.y);
        a0.z = fmaf(wv, v0.z, a0.z); a0.w = fmaf(wv, v0.w, a0.w);
        a1.x = fmaf(wv, v1.x, a1.x); a1.y = fmaf(wv, v1.y, a1.y);
        a1.z = fmaf(wv, v1.z, a1.z); a1.w = fmaf(wv, v1.w, a1.w);
    }
    float* o = out + (size_t)row * LD;
    *(float4*)(o + tid * 4) = a0;
    *(float4*)(o + 1024 + tid * 4) = a1;
}

extern "C" void kernel_launch(void* const* d_in, const int* in_sizes, int n_in,
                              void* d_out, int out_size, void* d_ws, size_t ws_size,
                              hipStream_t stream)
{
    const float* x      = (const float*)d_in[0];
    const float* gate   = (const float*)d_in[1];
    const float* up     = (const float*)d_in[2];
    const float* down   = (const float*)d_in[3];
    const int* layer_idx = (const int*)d_in[4];
    float* out = (float*)d_out;

    // ---- ws layout: small region, then big region (xh|wh|zk, reused for dT)
    const size_t NK = (size_t)LN * LK;
    const size_t NC_ = (size_t)LN * CAP;
    char* p = (char*)d_ws;
    int*   idx     = (int*)p;            p += NK * 4;
    float* gu      = (float*)p;          p += NK * 4;
    int*   band    = (int*)p;            p += NC_ * 4;
    int*   bandcnt = (int*)p;            p += (size_t)LN * 4;
    int*   ghist   = (int*)p;            p += (size_t)LI * 4;
    int*   offs    = (int*)p;            p += (size_t)LI * 4;
    int*   cursor  = (int*)p;            p += (size_t)LI * 4;
    int*   inv     = (int*)p;            p += NC_ * 4;
    float* gdot    = (float*)p;          p += NC_ * 4;
    float* udot    = (float*)p;          p += NC_ * 4;
    p = (char*)(((size_t)p + 255) & ~(size_t)255);

    const size_t xcnt = (size_t)LN * LD;
    const size_t wcnt = (size_t)LI * LD;
    unsigned short* xh = (unsigned short*)p;
    unsigned short* wh = xh + xcnt;
    unsigned short* zk = wh + wcnt;
    char* big_end = (char*)(zk + (size_t)LN * LI);
    float* dT = (float*)p;   // overlays xh|wh|zk after k_select (64 MB <= 72 MB)

    if ((size_t)(big_end - (char*)d_ws) > ws_size) return;   // ws too small

    k_cvt_h<<<512,  256, 0, stream>>>(x,    layer_idx, 0,    xh, (int)(xcnt / 4));
    k_cvt_h<<<2048, 256, 0, stream>>>(gate, layer_idx, wcnt, wh, (int)(wcnt / 4));
    k_gemm_z<<<dim3(LI / 128, LN / 128), 256, 0, stream>>>(xh, wh, zk);

    hipMemsetAsync(ghist, 0, (size_t)LI * 4, stream);
    k_select<<<LN, 256, 0, stream>>>(zk, band, bandcnt, ghist);
    k_scan<<<1, 256, 0, stream>>>(ghist, offs, cursor);
    k_scatter<<<LN, 256, 0, stream>>>(band, bandcnt, cursor, inv);
    k_pair<<<LI, 256, 0, stream>>>(x, gate, up, layer_idx, ghist, offs, inv, gdot, udot);
    k_final<<<LN, 256, 0, stream>>>(band, bandcnt, gdot, udot, idx, gu);

    k_transpose<<<dim3(LI / 32, LD / 32), 256, 0, stream>>>(down, layer_idx, dT);
    k_down<<<LN, 256, 0, stream>>>(dT, idx, gu, out);
}

// Round 8
// 334.391 us; speedup vs baseline: 1.2930x; 1.2930x over previous
//
#include <hip/hip_runtime.h>
#include <math.h>

constexpr int LI = 8192;   // I (intermediate)
constexpr int LD = 2048;   // D (hidden)
constexpr int LN = 2048;   // N (tokens)
constexpr int LK = 32;     // top_k
constexpr int CAP = 192;   // candidate band cap per row

typedef short short8 __attribute__((ext_vector_type(8)));
typedef unsigned short ushort8 __attribute__((ext_vector_type(8)));
typedef float f32x4 __attribute__((ext_vector_type(4)));
typedef const __attribute__((address_space(1))) void* gas1_t;
typedef __attribute__((address_space(3))) void* las3_t;

__device__ __forceinline__ void gload16(const void* g, void* l) {
    __builtin_amdgcn_global_load_lds((gas1_t)g, (las3_t)l, 16, 0, 0);
}
__device__ __forceinline__ unsigned short f2bf_rne(float f) {
    unsigned u = __float_as_uint(f);
    return (unsigned short)((u + 0x7fffu + ((u >> 16) & 1u)) >> 16);
}

// ---- fused fp32->bf16 convert: blocks [0,512) = x, [512,2560) = gate[l]
__global__ __launch_bounds__(256) void k_cvt2(
    const float* __restrict__ x, const float* __restrict__ gate,
    const int* __restrict__ layer_idx,
    unsigned short* __restrict__ xh, unsigned short* __restrict__ wh)
{
    const float* src; unsigned short* dst; int n4, bid, nb;
    if (blockIdx.x < 512) {
        src = x; dst = xh; n4 = (LN * LD) / 4; bid = blockIdx.x; nb = 512;
    } else {
        src = gate + (size_t)layer_idx[0] * LI * LD; dst = wh;
        n4 = (LI * LD) / 4; bid = blockIdx.x - 512; nb = 2048;
    }
    int i = bid * 256 + threadIdx.x;
    int stride = nb * 256;
    for (; i < n4; i += stride) {
        float4 v = ((const float4*)src)[i];
        ushort4 h = {f2bf_rne(v.x), f2bf_rne(v.y), f2bf_rne(v.z), f2bf_rne(v.w)};
        ((ushort4*)dst)[i] = h;
    }
}

// ---- zk = bf16(|silu(x @ gw^T)|) via bf16 MFMA, 128x128 tile, BK=64.
// Verified structure (rounds 4-7).
__global__ __launch_bounds__(256) void k_gemm_z(
    const unsigned short* __restrict__ xh, const unsigned short* __restrict__ wh,
    unsigned short* __restrict__ zk)
{
    __shared__ short lds[16384];   // Ah|Bh, each [128][64] bf16 = 16KB
    short* Ah = lds;
    short* Bh = lds + 8192;

    const int tid = threadIdx.x;
    const int w = tid >> 6, lane = tid & 63;
    const int bn = blockIdx.y * 128;
    const int bi = blockIdx.x * 128;

    const int srow   = w * 32 + (lane >> 3);
    const int schunk = (lane & 7) ^ ((lane >> 3) & 7);
    const unsigned short* xbh = xh + (size_t)(bn + srow) * LD + schunk * 8;
    const unsigned short* wbh = wh + (size_t)(bi + srow) * LD + schunk * 8;

    f32x4 acc[4][4];
    #pragma unroll
    for (int m = 0; m < 4; ++m)
        #pragma unroll
        for (int n = 0; n < 4; ++n) acc[m][n] = (f32x4){0.f, 0.f, 0.f, 0.f};

    const int wm = (w >> 1) * 64, wn = (w & 1) * 64;

    #define STAGE(k0)                                                          \
        {                                                                      \
            _Pragma("unroll")                                                  \
            for (int t = 0; t < 4; ++t) {                                      \
                int ldo = (w * 32 + t * 8) * 64;                               \
                size_t go = (size_t)t * 8 * LD + (k0);                         \
                gload16(xbh + go, Ah + ldo);                                   \
                gload16(wbh + go, Bh + ldo);                                   \
            }                                                                  \
        }

    STAGE(0);
    __syncthreads();
    for (int k0 = 0;;) {
        #pragma unroll
        for (int ks = 0; ks < 2; ++ks) {
            short8 a_h[4], b_h[4];
            #pragma unroll
            for (int m = 0; m < 4; ++m) {
                int lr = wm + m * 16 + (lane & 15);
                int lc = ks * 4 + (lane >> 4);
                a_h[m] = *(const short8*)(Ah + lr * 64 + ((lc ^ (lr & 7)) << 3));
            }
            #pragma unroll
            for (int n = 0; n < 4; ++n) {
                int lr = wn + n * 16 + (lane & 15);
                int lc = ks * 4 + (lane >> 4);
                b_h[n] = *(const short8*)(Bh + lr * 64 + ((lc ^ (lr & 7)) << 3));
            }
            #pragma unroll
            for (int m = 0; m < 4; ++m)
                #pragma unroll
                for (int n = 0; n < 4; ++n)
                    acc[m][n] = __builtin_amdgcn_mfma_f32_16x16x32_bf16(a_h[m], b_h[n], acc[m][n], 0, 0, 0);
        }
        k0 += 64;
        if (k0 >= LD) break;
        __syncthreads();
        STAGE(k0);
        __syncthreads();
    }

    #pragma unroll
    for (int m = 0; m < 4; ++m) {
        int rb = bn + wm + m * 16 + (lane >> 4) * 4;
        #pragma unroll
        for (int n = 0; n < 4; ++n) {
            int cb = bi + wn + n * 16 + (lane & 15);
            #pragma unroll
            for (int r = 0; r < 4; ++r) {
                float zv = acc[m][n][r];
                float g = zv / (1.f + expf(-zv));
                zk[(size_t)(rb + r) * LI + cb] = f2bf_rne(fabsf(g));
            }
        }
    }
    #undef STAGE
}

// ---- band selection: bf16-ulp histogram (1024 bins over [0.25,64)),
// threshold bin covering rank-32, band = keys >= binfloor - MARGIN.
// Band order is irrelevant (k_final re-sorts) -> barrier-free compaction.
__global__ __launch_bounds__(256) void k_select(
    const unsigned short* __restrict__ zk, int* __restrict__ band,
    int* __restrict__ bandcnt, int* __restrict__ ghist)
{
    __shared__ int hist[1024];   // 4 KB
    __shared__ int sums[256];
    __shared__ int base_s;
    __shared__ int thrbin_s;

    const int row = blockIdx.x;
    const int tid = threadIdx.x;
    const int lane = tid & 63;
    const unsigned short* __restrict__ z = zk + (size_t)row * LI;

    if (tid == 0) { thrbin_s = 0; base_s = 0; }
    for (int i = tid; i < 1024; i += 256) hist[i] = 0;
    __syncthreads();
    for (int i = tid; i < LI; i += 256) {
        int b = (int)z[i] - 0x3E80;            // bf16 bits of 0.25
        b = b < 0 ? 0 : (b > 1023 ? 1023 : b);
        atomicAdd(&hist[b], 1);
    }
    __syncthreads();

    int own = 0;
    #pragma unroll
    for (int b = 0; b < 4; ++b) own += hist[tid * 4 + b];
    sums[tid] = own;
    __syncthreads();
    for (int st = 1; st < 256; st <<= 1) {   // suffix inclusive scan
        int v = (tid + st < 256) ? sums[tid + st] : 0;
        __syncthreads();
        sums[tid] += v;
        __syncthreads();
    }
    int after = (tid < 255) ? sums[tid + 1] : 0;
    if (after < LK && after + own >= LK) {   // unique crossing thread
        int cum = after;
        for (int b = 3; b >= 0; --b) {
            cum += hist[tid * 4 + b];
            if (cum >= LK) { thrbin_s = tid * 4 + b; break; }
        }
    }
    __syncthreads();
    const float bandlo =
        __uint_as_float((unsigned)(0x3E80 + thrbin_s) << 16) - 0.06f;

    for (int c0 = 0; c0 < LI; c0 += 256) {
        float kf = __uint_as_float(((unsigned)z[c0 + tid]) << 16);
        bool f = kf >= bandlo;
        unsigned long long m = __ballot(f);
        int pos0 = 0;
        if (lane == 0) pos0 = atomicAdd(&base_s, __popcll(m));
        pos0 = __shfl(pos0, 0);
        int pos = pos0 + __popcll(m & ((1ull << lane) - 1ull));
        if (f && pos < CAP) {
            band[row * CAP + pos] = c0 + tid;
            atomicAdd(&ghist[c0 + tid], 1);
        }
    }
    __syncthreads();
    if (tid == 0) bandcnt[row] = base_s < CAP ? base_s : CAP;
}

// ---- exclusive prefix-sum of ghist[8192] -> offs, cursor (single block)
__global__ __launch_bounds__(256) void k_scan(
    const int* __restrict__ ghist, int* __restrict__ offs, int* __restrict__ cursor)
{
    __shared__ int sums[256];
    const int tid = threadIdx.x;
    int loc[32];
    int s = 0;
    #pragma unroll
    for (int b = 0; b < 32; ++b) { loc[b] = s; s += ghist[tid * 32 + b]; }
    sums[tid] = s;
    __syncthreads();
    for (int st = 1; st < 256; st <<= 1) {
        int v = (tid >= st) ? sums[tid - st] : 0;
        __syncthreads();
        sums[tid] += v;
        __syncthreads();
    }
    int base = (tid > 0) ? sums[tid - 1] : 0;
    #pragma unroll
    for (int b = 0; b < 32; ++b) {
        int o = base + loc[b];
        offs[tid * 32 + b]   = o;
        cursor[tid * 32 + b] = o;
    }
}

// ---- scatter band entries into neuron-major inverted list
__global__ __launch_bounds__(256) void k_scatter(
    const int* __restrict__ band, const int* __restrict__ bandcnt,
    int* __restrict__ cursor, int* __restrict__ inv)
{
    const int row = blockIdx.x;
    const int tid = threadIdx.x;
    int cnt = bandcnt[row];
    if (tid < cnt) {
        int j = band[row * CAP + tid] & (LI - 1);
        int p = atomicAdd(&cursor[j], 1);
        inv[p] = (row << 8) | tid;
    }
}

// ---- FUSED: blocks [0,LI) = neuron-major exact rescore (k_pair);
//             blocks [LI, LI+4096) = transpose down[D,I] -> dT bf16 [I,D].
// Independent work co-scheduled: pair is latency-bound, transpose BW-bound.
__global__ __launch_bounds__(256) void k_pairT(
    const float* __restrict__ x, const float* __restrict__ gate,
    const float* __restrict__ up, const float* __restrict__ down,
    const int* __restrict__ layer_idx,
    const int* __restrict__ ghist, const int* __restrict__ offs,
    const int* __restrict__ inv,
    float* __restrict__ gdot, float* __restrict__ udot,
    unsigned short* __restrict__ dTb)
{
    __shared__ float smem[4160];   // pair: gs|us (16 KB); transpose: 64x65 tile
    const int tid = threadIdx.x;

    if (blockIdx.x < LI) {
        // ---------------- pair body (verified round 7) ----------------
        float* gs = smem;
        float* us = smem + LD;
        const int j = blockIdx.x;
        const int lane = tid & 63, w = tid >> 6;
        const int nj = ghist[j];
        if (nj == 0) return;
        const float* __restrict__ gr = gate + (size_t)layer_idx[0] * LI * LD + (size_t)j * LD;
        const float* __restrict__ ur = up   + (size_t)layer_idx[0] * LI * LD + (size_t)j * LD;
        for (int i = tid * 4; i < LD; i += 1024) {
            *(float4*)&gs[i] = *(const float4*)(gr + i);
            *(float4*)&us[i] = *(const float4*)(ur + i);
        }
        __syncthreads();
        const int base = offs[j];
        for (int e = w; e < nj; e += 4) {
            int packed = inv[base + e];
            int row = packed >> 8, slot = packed & 255;
            const float* __restrict__ xr = x + (size_t)row * LD;
            float gd = 0.f, ud = 0.f;
            for (int i = lane * 4; i < LD; i += 256) {
                float4 xv = *(const float4*)(xr + i);
                gd = fmaf(xv.x, gs[i+0], gd); gd = fmaf(xv.y, gs[i+1], gd);
                gd = fmaf(xv.z, gs[i+2], gd); gd = fmaf(xv.w, gs[i+3], gd);
                ud = fmaf(xv.x, us[i+0], ud); ud = fmaf(xv.y, us[i+1], ud);
                ud = fmaf(xv.z, us[i+2], ud); ud = fmaf(xv.w, us[i+3], ud);
            }
            #pragma unroll
            for (int o = 32; o; o >>= 1) {
                gd += __shfl_down(gd, o);
                ud += __shfl_down(ud, o);
            }
            if (lane == 0) {
                gdot[(size_t)row * CAP + slot] = gd;
                udot[(size_t)row * CAP + slot] = ud;
            }
        }
    } else {
        // ---------------- transpose body: 64x64 tiles, bf16 out -------
        float (*t)[65] = (float(*)[65])smem;
        const float* __restrict__ dw = down + (size_t)layer_idx[0] * LD * LI;
        const int bid2 = blockIdx.x - LI;
        const int bi = (bid2 & 127) * 64;   // I
        const int bd = (bid2 >> 7) * 64;    // D
        const int tx = tid & 63, ty = tid >> 6;
        #pragma unroll
        for (int it = 0; it < 16; ++it) {
            int r = ty + it * 4;
            t[r][tx] = dw[(size_t)(bd + r) * LI + bi + tx];
        }
        __syncthreads();
        #pragma unroll
        for (int it = 0; it < 16; ++it) {
            int rr = ty + it * 4;
            dTb[(size_t)(bi + rr) * LD + bd + tx] = f2bf_rne(t[tx][rr]);
        }
    }
}

// ---- per-row exact top-32 among band (desc exact key, asc idx); gu = silu*u
__global__ __launch_bounds__(256) void k_final(
    const int* __restrict__ band, const int* __restrict__ bandcnt,
    const float* __restrict__ gdot, const float* __restrict__ udot,
    int* __restrict__ idx_out, float* __restrict__ gu_out)
{
    __shared__ float ckey[CAP];
    __shared__ float cgu[CAP];
    __shared__ int   cidx[CAP];
    const int row = blockIdx.x;
    const int tid = threadIdx.x;
    const int lane = tid & 63;
    const int cnt = bandcnt[row];
    if (tid < CAP) { ckey[tid] = -1.f; cgu[tid] = 0.f; cidx[tid] = 0x7fffffff; }
    __syncthreads();
    if (tid < cnt) {
        float gd = gdot[(size_t)row * CAP + tid];
        float g = gd / (1.f + expf(-gd));
        ckey[tid] = fabsf(g);
        cgu[tid]  = g * udot[(size_t)row * CAP + tid];
        cidx[tid] = band[row * CAP + tid];
    }
    __syncthreads();
    if (tid < 64) {
        float k1 = ckey[lane], k2 = ckey[lane + 64], k3 = ckey[lane + 128];
        int   i1 = cidx[lane], i2 = cidx[lane + 64], i3 = cidx[lane + 128];
        int   p1 = lane, p2 = lane + 64, p3 = lane + 128;
        for (int slot = 0; slot < LK; ++slot) {
            float bk = k1; int bi_ = i1, bp = p1;
            if (k2 > bk || (k2 == bk && i2 < bi_)) { bk = k2; bi_ = i2; bp = p2; }
            if (k3 > bk || (k3 == bk && i3 < bi_)) { bk = k3; bi_ = i3; bp = p3; }
            #pragma unroll
            for (int o = 1; o < 64; o <<= 1) {
                float ok = __shfl_xor(bk, o);
                int  oi = __shfl_xor(bi_, o);
                int  op = __shfl_xor(bp, o);
                if (ok > bk || (ok == bk && oi < bi_)) { bk = ok; bi_ = oi; bp = op; }
            }
            if (lane == 0) {
                idx_out[row * LK + slot] = bi_ & (LI - 1);
                gu_out[row * LK + slot]  = cgu[bp < CAP ? bp : 0];
            }
            if (p1 == bp) { k1 = -1.f; i1 = 0x7fffffff; }
            if (p2 == bp) { k2 = -1.f; i2 = 0x7fffffff; }
            if (p3 == bp) { k3 = -1.f; i3 = 0x7fffffff; }
        }
    }
}

// ---- out[n,:] = sum_k gu[n,k] * dTb[idx[n,k], :]   (bf16 gathered rows)
__global__ __launch_bounds__(256) void k_down(
    const unsigned short* __restrict__ dTb, const int* __restrict__ idx,
    const float* __restrict__ gu, float* __restrict__ out)
{
    __shared__ int   js[LK];
    __shared__ float wgt[LK];
    const int row = blockIdx.x;
    const int tid = threadIdx.x;
    if (tid < LK) {
        js[tid]  = idx[row * LK + tid] & (LI - 1);
        wgt[tid] = gu[row * LK + tid];
    }
    __syncthreads();
    float a[8] = {0.f,0.f,0.f,0.f,0.f,0.f,0.f,0.f};
    #pragma unroll 4
    for (int k = 0; k < LK; ++k) {
        const ushort8 v = *(const ushort8*)(dTb + (size_t)js[k] * LD + tid * 8);
        float wv = wgt[k];
        #pragma unroll
        for (int e = 0; e < 8; ++e)
            a[e] = fmaf(wv, __uint_as_float(((unsigned)v[e]) << 16), a[e]);
    }
    float* o = out + (size_t)row * LD + tid * 8;
    float4 o0 = {a[0], a[1], a[2], a[3]};
    float4 o1 = {a[4], a[5], a[6], a[7]};
    *(float4*)o = o0;
    *(float4*)(o + 4) = o1;
}

extern "C" void kernel_launch(void* const* d_in, const int* in_sizes, int n_in,
                              void* d_out, int out_size, void* d_ws, size_t ws_size,
                              hipStream_t stream)
{
    const float* x      = (const float*)d_in[0];
    const float* gate   = (const float*)d_in[1];
    const float* up     = (const float*)d_in[2];
    const float* down   = (const float*)d_in[3];
    const int* layer_idx = (const int*)d_in[4];
    float* out = (float*)d_out;

    // ---- ws layout: small region, then big region (xh|wh|zk, reused for dTb)
    const size_t NK = (size_t)LN * LK;
    const size_t NC_ = (size_t)LN * CAP;
    char* p = (char*)d_ws;
    int*   idx     = (int*)p;            p += NK * 4;
    float* gu      = (float*)p;          p += NK * 4;
    int*   band    = (int*)p;            p += NC_ * 4;
    int*   bandcnt = (int*)p;            p += (size_t)LN * 4;
    int*   ghist   = (int*)p;            p += (size_t)LI * 4;
    int*   offs    = (int*)p;            p += (size_t)LI * 4;
    int*   cursor  = (int*)p;            p += (size_t)LI * 4;
    int*   inv     = (int*)p;            p += NC_ * 4;
    float* gdot    = (float*)p;          p += NC_ * 4;
    float* udot    = (float*)p;          p += NC_ * 4;
    p = (char*)(((size_t)p + 255) & ~(size_t)255);

    const size_t xcnt = (size_t)LN * LD;
    const size_t wcnt = (size_t)LI * LD;
    unsigned short* xh = (unsigned short*)p;
    unsigned short* wh = xh + xcnt;
    unsigned short* zk = wh + wcnt;
    char* big_end = (char*)(zk + (size_t)LN * LI);
    // dTb (bf16, 32 MB) overlays xh|wh (40 MB) — both dead after k_gemm_z.
    unsigned short* dTb = (unsigned short*)p;

    if ((size_t)(big_end - (char*)d_ws) > ws_size) return;   // ws too small

    k_cvt2<<<2560, 256, 0, stream>>>(x, gate, layer_idx, xh, wh);
    k_gemm_z<<<dim3(LI / 128, LN / 128), 256, 0, stream>>>(xh, wh, zk);

    hipMemsetAsync(ghist, 0, (size_t)LI * 4, stream);
    k_select<<<LN, 256, 0, stream>>>(zk, band, bandcnt, ghist);
    k_scan<<<1, 256, 0, stream>>>(ghist, offs, cursor);
    k_scatter<<<LN, 256, 0, stream>>>(band, bandcnt, cursor, inv);
    k_pairT<<<LI + 4096, 256, 0, stream>>>(x, gate, up, down, layer_idx,
                                           ghist, offs, inv, gdot, udot, dTb);
    k_final<<<LN, 256, 0, stream>>>(band, bandcnt, gdot, udot, idx, gu);
    k_down<<<LN, 256, 0, stream>>>(dTb, idx, gu, out);
}

// Round 9
// 314.029 us; speedup vs baseline: 1.3768x; 1.0648x over previous
//
#include <hip/hip_runtime.h>
#include <math.h>

constexpr int LI = 8192;   // I (intermediate)
constexpr int LD = 2048;   // D (hidden)
constexpr int LN = 2048;   // N (tokens)
constexpr int LK = 32;     // top_k
constexpr int CAP = 192;   // candidate band cap per row

typedef short short8 __attribute__((ext_vector_type(8)));
typedef unsigned short ushort8 __attribute__((ext_vector_type(8)));
typedef float f32x4 __attribute__((ext_vector_type(4)));
typedef const __attribute__((address_space(1))) void* gas1_t;
typedef __attribute__((address_space(3))) void* las3_t;

__device__ __forceinline__ void gload16(const void* g, void* l) {
    __builtin_amdgcn_global_load_lds((gas1_t)g, (las3_t)l, 16, 0, 0);
}
__device__ __forceinline__ unsigned short f2bf_rne(float f) {
    unsigned u = __float_as_uint(f);
    return (unsigned short)((u + 0x7fffu + ((u >> 16) & 1u)) >> 16);
}

// ---- fused fp32->bf16 convert: blocks [0,512) = x, [512,2560) = gate[l]
__global__ __launch_bounds__(256) void k_cvt2(
    const float* __restrict__ x, const float* __restrict__ gate,
    const int* __restrict__ layer_idx,
    unsigned short* __restrict__ xh, unsigned short* __restrict__ wh)
{
    const float* src; unsigned short* dst; int n4, bid, nb;
    if (blockIdx.x < 512) {
        src = x; dst = xh; n4 = (LN * LD) / 4; bid = blockIdx.x; nb = 512;
    } else {
        src = gate + (size_t)layer_idx[0] * LI * LD; dst = wh;
        n4 = (LI * LD) / 4; bid = blockIdx.x - 512; nb = 2048;
    }
    int i = bid * 256 + threadIdx.x;
    int stride = nb * 256;
    for (; i < n4; i += stride) {
        float4 v = ((const float4*)src)[i];
        ushort4 h = {f2bf_rne(v.x), f2bf_rne(v.y), f2bf_rne(v.z), f2bf_rne(v.w)};
        ((ushort4*)dst)[i] = h;
    }
}

// ---- zk = bf16(|silu(x @ gw^T)|) via bf16 MFMA, 128x128 tile, BK=64.
// Verified structure (rounds 4-8). UNCHANGED.
__global__ __launch_bounds__(256) void k_gemm_z(
    const unsigned short* __restrict__ xh, const unsigned short* __restrict__ wh,
    unsigned short* __restrict__ zk)
{
    __shared__ short lds[16384];   // Ah|Bh, each [128][64] bf16 = 16KB
    short* Ah = lds;
    short* Bh = lds + 8192;

    const int tid = threadIdx.x;
    const int w = tid >> 6, lane = tid & 63;
    const int bn = blockIdx.y * 128;
    const int bi = blockIdx.x * 128;

    const int srow   = w * 32 + (lane >> 3);
    const int schunk = (lane & 7) ^ ((lane >> 3) & 7);
    const unsigned short* xbh = xh + (size_t)(bn + srow) * LD + schunk * 8;
    const unsigned short* wbh = wh + (size_t)(bi + srow) * LD + schunk * 8;

    f32x4 acc[4][4];
    #pragma unroll
    for (int m = 0; m < 4; ++m)
        #pragma unroll
        for (int n = 0; n < 4; ++n) acc[m][n] = (f32x4){0.f, 0.f, 0.f, 0.f};

    const int wm = (w >> 1) * 64, wn = (w & 1) * 64;

    #define STAGE(k0)                                                          \
        {                                                                      \
            _Pragma("unroll")                                                  \
            for (int t = 0; t < 4; ++t) {                                      \
                int ldo = (w * 32 + t * 8) * 64;                               \
                size_t go = (size_t)t * 8 * LD + (k0);                         \
                gload16(xbh + go, Ah + ldo);                                   \
                gload16(wbh + go, Bh + ldo);                                   \
            }                                                                  \
        }

    STAGE(0);
    __syncthreads();
    for (int k0 = 0;;) {
        #pragma unroll
        for (int ks = 0; ks < 2; ++ks) {
            short8 a_h[4], b_h[4];
            #pragma unroll
            for (int m = 0; m < 4; ++m) {
                int lr = wm + m * 16 + (lane & 15);
                int lc = ks * 4 + (lane >> 4);
                a_h[m] = *(const short8*)(Ah + lr * 64 + ((lc ^ (lr & 7)) << 3));
            }
            #pragma unroll
            for (int n = 0; n < 4; ++n) {
                int lr = wn + n * 16 + (lane & 15);
                int lc = ks * 4 + (lane >> 4);
                b_h[n] = *(const short8*)(Bh + lr * 64 + ((lc ^ (lr & 7)) << 3));
            }
            #pragma unroll
            for (int m = 0; m < 4; ++m)
                #pragma unroll
                for (int n = 0; n < 4; ++n)
                    acc[m][n] = __builtin_amdgcn_mfma_f32_16x16x32_bf16(a_h[m], b_h[n], acc[m][n], 0, 0, 0);
        }
        k0 += 64;
        if (k0 >= LD) break;
        __syncthreads();
        STAGE(k0);
        __syncthreads();
    }

    #pragma unroll
    for (int m = 0; m < 4; ++m) {
        int rb = bn + wm + m * 16 + (lane >> 4) * 4;
        #pragma unroll
        for (int n = 0; n < 4; ++n) {
            int cb = bi + wn + n * 16 + (lane & 15);
            #pragma unroll
            for (int r = 0; r < 4; ++r) {
                float zv = acc[m][n][r];
                float g = zv / (1.f + expf(-zv));
                zk[(size_t)(rb + r) * LI + cb] = f2bf_rne(fabsf(g));
            }
        }
    }
    #undef STAGE
}

// ---- band selection: bf16-ulp histogram (1024 bins over [0.25,64)),
// threshold bin covering rank-32, band = keys >= binfloor - MARGIN.
// Vectorized: keys held in registers across both phases; wave-scan compaction.
__global__ __launch_bounds__(256) void k_select(
    const unsigned short* __restrict__ zk, int* __restrict__ band,
    int* __restrict__ bandcnt, int* __restrict__ ghist)
{
    __shared__ int hist[1024];   // 4 KB
    __shared__ int sums[256];
    __shared__ int base_s;
    __shared__ int thrbin_s;

    const int row = blockIdx.x;
    const int tid = threadIdx.x;
    const int lane = tid & 63;
    const unsigned short* __restrict__ z = zk + (size_t)row * LI;

    if (tid == 0) { thrbin_s = 0; base_s = 0; }
    for (int i = tid; i < 1024; i += 256) hist[i] = 0;
    __syncthreads();

    // phase 1: vectorized load (keys stay in registers) + histogram
    ushort8 kv[4];
    #pragma unroll
    for (int c = 0; c < 4; ++c) {
        kv[c] = *(const ushort8*)(z + c * 2048 + tid * 8);
        #pragma unroll
        for (int j = 0; j < 8; ++j) {
            int b = (int)kv[c][j] - 0x3E80;            // bf16 bits of 0.25
            b = b < 0 ? 0 : (b > 1023 ? 1023 : b);
            atomicAdd(&hist[b], 1);
        }
    }
    __syncthreads();

    int own = 0;
    #pragma unroll
    for (int b = 0; b < 4; ++b) own += hist[tid * 4 + b];
    sums[tid] = own;
    __syncthreads();
    for (int st = 1; st < 256; st <<= 1) {   // suffix inclusive scan
        int v = (tid + st < 256) ? sums[tid + st] : 0;
        __syncthreads();
        sums[tid] += v;
        __syncthreads();
    }
    int after = (tid < 255) ? sums[tid + 1] : 0;
    if (after < LK && after + own >= LK) {   // unique crossing thread
        int cum = after;
        for (int b = 3; b >= 0; --b) {
            cum += hist[tid * 4 + b];
            if (cum >= LK) { thrbin_s = tid * 4 + b; break; }
        }
    }
    __syncthreads();
    const float bandlo =
        __uint_as_float((unsigned)(0x3E80 + thrbin_s) << 16) - 0.06f;

    // phase 2: band compaction from registers (order irrelevant; re-sorted later)
    #pragma unroll
    for (int c = 0; c < 4; ++c) {
        unsigned flags = 0;
        #pragma unroll
        for (int j = 0; j < 8; ++j) {
            float kf = __uint_as_float(((unsigned)kv[c][j]) << 16);
            if (kf >= bandlo) flags |= (1u << j);
        }
        int cnt = __popc(flags);
        int pre = cnt;                        // wave inclusive scan
        #pragma unroll
        for (int o = 1; o < 64; o <<= 1) {
            int v = __shfl_up(pre, o);
            if (lane >= o) pre += v;
        }
        int wtotal = __shfl(pre, 63);
        int excl = pre - cnt;
        int wbase = 0;
        if (lane == 63 && wtotal) wbase = atomicAdd(&base_s, wtotal);
        wbase = __shfl(wbase, 63);
        int pos = wbase + excl;
        while (flags) {
            int j = __ffs(flags) - 1;
            flags &= flags - 1;
            if (pos < CAP) {
                int gi = c * 2048 + tid * 8 + j;
                band[row * CAP + pos] = gi;
                atomicAdd(&ghist[gi], 1);
            }
            ++pos;
        }
    }
    __syncthreads();
    if (tid == 0) bandcnt[row] = base_s < CAP ? base_s : CAP;
}

// ---- exclusive prefix-sum of ghist[8192] -> offs, cursor (single block)
__global__ __launch_bounds__(256) void k_scan(
    const int* __restrict__ ghist, int* __restrict__ offs, int* __restrict__ cursor)
{
    __shared__ int sums[256];
    const int tid = threadIdx.x;
    int loc[32];
    int s = 0;
    #pragma unroll
    for (int b = 0; b < 32; ++b) { loc[b] = s; s += ghist[tid * 32 + b]; }
    sums[tid] = s;
    __syncthreads();
    for (int st = 1; st < 256; st <<= 1) {
        int v = (tid >= st) ? sums[tid - st] : 0;
        __syncthreads();
        sums[tid] += v;
        __syncthreads();
    }
    int base = (tid > 0) ? sums[tid - 1] : 0;
    #pragma unroll
    for (int b = 0; b < 32; ++b) {
        int o = base + loc[b];
        offs[tid * 32 + b]   = o;
        cursor[tid * 32 + b] = o;
    }
}

// ---- scatter band entries into neuron-major inverted list
__global__ __launch_bounds__(256) void k_scatter(
    const int* __restrict__ band, const int* __restrict__ bandcnt,
    int* __restrict__ cursor, int* __restrict__ inv)
{
    const int row = blockIdx.x;
    const int tid = threadIdx.x;
    int cnt = bandcnt[row];
    if (tid < cnt) {
        int j = band[row * CAP + tid] & (LI - 1);
        int p = atomicAdd(&cursor[j], 1);
        inv[p] = (row << 8) | tid;
    }
}

// ---- FUSED: blocks [0,LI) = neuron-major exact rescore (pair);
//             blocks [LI, LI+4096) = transpose down[D,I] -> dT bf16 [I,D].
// Pair dot loop fully unrolled (8 outstanding x-loads) + dual accumulators.
__global__ __launch_bounds__(256) void k_pairT(
    const float* __restrict__ x, const float* __restrict__ gate,
    const float* __restrict__ up, const float* __restrict__ down,
    const int* __restrict__ layer_idx,
    const int* __restrict__ ghist, const int* __restrict__ offs,
    const int* __restrict__ inv,
    float* __restrict__ gdot, float* __restrict__ udot,
    unsigned short* __restrict__ dTb)
{
    __shared__ float smem[4160];   // pair: gs|us (16 KB); transpose: 64x65 tile
    const int tid = threadIdx.x;

    if (blockIdx.x < LI) {
        // ---------------- pair body ----------------
        float* gs = smem;
        float* us = smem + LD;
        const int j = blockIdx.x;
        const int lane = tid & 63, w = tid >> 6;
        const int nj = ghist[j];
        if (nj == 0) return;
        const float* __restrict__ gr = gate + (size_t)layer_idx[0] * LI * LD + (size_t)j * LD;
        const float* __restrict__ ur = up   + (size_t)layer_idx[0] * LI * LD + (size_t)j * LD;
        for (int i = tid * 4; i < LD; i += 1024) {
            *(float4*)&gs[i] = *(const float4*)(gr + i);
            *(float4*)&us[i] = *(const float4*)(ur + i);
        }
        __syncthreads();
        const int base = offs[j];
        for (int e = w; e < nj; e += 4) {
            int packed = inv[base + e];
            int row = packed >> 8, slot = packed & 255;
            const float* __restrict__ xr = x + (size_t)row * LD;
            float gd0 = 0.f, gd1 = 0.f, ud0 = 0.f, ud1 = 0.f;
            #pragma unroll
            for (int it = 0; it < 8; it += 2) {
                int i0 = lane * 4 + it * 256;
                int i1 = i0 + 256;
                float4 xa = *(const float4*)(xr + i0);
                float4 xb = *(const float4*)(xr + i1);
                gd0 = fmaf(xa.x, gs[i0+0], gd0); gd0 = fmaf(xa.y, gs[i0+1], gd0);
                gd0 = fmaf(xa.z, gs[i0+2], gd0); gd0 = fmaf(xa.w, gs[i0+3], gd0);
                ud0 = fmaf(xa.x, us[i0+0], ud0); ud0 = fmaf(xa.y, us[i0+1], ud0);
                ud0 = fmaf(xa.z, us[i0+2], ud0); ud0 = fmaf(xa.w, us[i0+3], ud0);
                gd1 = fmaf(xb.x, gs[i1+0], gd1); gd1 = fmaf(xb.y, gs[i1+1], gd1);
                gd1 = fmaf(xb.z, gs[i1+2], gd1); gd1 = fmaf(xb.w, gs[i1+3], gd1);
                ud1 = fmaf(xb.x, us[i1+0], ud1); ud1 = fmaf(xb.y, us[i1+1], ud1);
                ud1 = fmaf(xb.z, us[i1+2], ud1); ud1 = fmaf(xb.w, us[i1+3], ud1);
            }
            float gd = gd0 + gd1, ud = ud0 + ud1;
            #pragma unroll
            for (int o = 32; o; o >>= 1) {
                gd += __shfl_down(gd, o);
                ud += __shfl_down(ud, o);
            }
            if (lane == 0) {
                gdot[(size_t)row * CAP + slot] = gd;
                udot[(size_t)row * CAP + slot] = ud;
            }
        }
    } else {
        // ---------------- transpose body: 64x64 tiles, bf16 out -------
        float (*t)[65] = (float(*)[65])smem;
        const float* __restrict__ dw = down + (size_t)layer_idx[0] * LD * LI;
        const int bid2 = blockIdx.x - LI;
        const int bi = (bid2 & 127) * 64;   // I
        const int bd = (bid2 >> 7) * 64;    // D
        const int tx = tid & 63, ty = tid >> 6;
        #pragma unroll
        for (int it = 0; it < 16; ++it) {
            int r = ty + it * 4;
            t[r][tx] = dw[(size_t)(bd + r) * LI + bi + tx];
        }
        __syncthreads();
        #pragma unroll
        for (int it = 0; it < 16; ++it) {
            int rr = ty + it * 4;
            dTb[(size_t)(bi + rr) * LD + bd + tx] = f2bf_rne(t[tx][rr]);
        }
    }
}

// ---- FUSED final: per-row exact top-32 among band (desc exact key, asc idx),
// gu = silu*u, then down-gather: out[n,:] = sum_k gu_k * dTb[idx_k, :]
__global__ __launch_bounds__(256) void k_finaldown(
    const int* __restrict__ band, const int* __restrict__ bandcnt,
    const float* __restrict__ gdot, const float* __restrict__ udot,
    const unsigned short* __restrict__ dTb, float* __restrict__ out)
{
    __shared__ float ckey[CAP];
    __shared__ float cgu[CAP];
    __shared__ int   cidx[CAP];
    __shared__ int   js[LK];
    __shared__ float wgt[LK];
    const int row = blockIdx.x;
    const int tid = threadIdx.x;
    const int lane = tid & 63;
    const int cnt = bandcnt[row];
    if (tid < CAP) { ckey[tid] = -1.f; cgu[tid] = 0.f; cidx[tid] = 0x7fffffff; }
    __syncthreads();
    if (tid < cnt) {
        float gd = gdot[(size_t)row * CAP + tid];
        float g = gd / (1.f + expf(-gd));
        ckey[tid] = fabsf(g);
        cgu[tid]  = g * udot[(size_t)row * CAP + tid];
        cidx[tid] = band[row * CAP + tid];
    }
    __syncthreads();
    if (tid < 64) {
        float k1 = ckey[lane], k2 = ckey[lane + 64], k3 = ckey[lane + 128];
        int   i1 = cidx[lane], i2 = cidx[lane + 64], i3 = cidx[lane + 128];
        int   p1 = lane, p2 = lane + 64, p3 = lane + 128;
        for (int slot = 0; slot < LK; ++slot) {
            float bk = k1; int bi_ = i1, bp = p1;
            if (k2 > bk || (k2 == bk && i2 < bi_)) { bk = k2; bi_ = i2; bp = p2; }
            if (k3 > bk || (k3 == bk && i3 < bi_)) { bk = k3; bi_ = i3; bp = p3; }
            #pragma unroll
            for (int o = 1; o < 64; o <<= 1) {
                float ok = __shfl_xor(bk, o);
                int  oi = __shfl_xor(bi_, o);
                int  op = __shfl_xor(bp, o);
                if (ok > bk || (ok == bk && oi < bi_)) { bk = ok; bi_ = oi; bp = op; }
            }
            if (lane == 0) {
                js[slot]  = bi_ & (LI - 1);
                wgt[slot] = cgu[bp < CAP ? bp : 0];
            }
            if (p1 == bp) { k1 = -1.f; i1 = 0x7fffffff; }
            if (p2 == bp) { k2 = -1.f; i2 = 0x7fffffff; }
            if (p3 == bp) { k3 = -1.f; i3 = 0x7fffffff; }
        }
    }
    __syncthreads();

    // down-gather (bf16 rows)
    float a[8] = {0.f,0.f,0.f,0.f,0.f,0.f,0.f,0.f};
    #pragma unroll 4
    for (int k = 0; k < LK; ++k) {
        const ushort8 v = *(const ushort8*)(dTb + (size_t)js[k] * LD + tid * 8);
        float wv = wgt[k];
        #pragma unroll
        for (int e = 0; e < 8; ++e)
            a[e] = fmaf(wv, __uint_as_float(((unsigned)v[e]) << 16), a[e]);
    }
    float* o = out + (size_t)row * LD + tid * 8;
    float4 o0 = {a[0], a[1], a[2], a[3]};
    float4 o1 = {a[4], a[5], a[6], a[7]};
    *(float4*)o = o0;
    *(float4*)(o + 4) = o1;
}

extern "C" void kernel_launch(void* const* d_in, const int* in_sizes, int n_in,
                              void* d_out, int out_size, void* d_ws, size_t ws_size,
                              hipStream_t stream)
{
    const float* x      = (const float*)d_in[0];
    const float* gate   = (const float*)d_in[1];
    const float* up     = (const float*)d_in[2];
    const float* down   = (const float*)d_in[3];
    const int* layer_idx = (const int*)d_in[4];
    float* out = (float*)d_out;

    // ---- ws layout: small region, then big region (xh|wh|zk, reused for dTb)
    const size_t NK = (size_t)LN * LK;
    const size_t NC_ = (size_t)LN * CAP;
    char* p = (char*)d_ws;
    p += NK * 4;                          // (reserved, unused)
    p += NK * 4;                          // (reserved, unused)
    int*   band    = (int*)p;            p += NC_ * 4;
    int*   bandcnt = (int*)p;            p += (size_t)LN * 4;
    int*   ghist   = (int*)p;            p += (size_t)LI * 4;
    int*   offs    = (int*)p;            p += (size_t)LI * 4;
    int*   cursor  = (int*)p;            p += (size_t)LI * 4;
    int*   inv     = (int*)p;            p += NC_ * 4;
    float* gdot    = (float*)p;          p += NC_ * 4;
    float* udot    = (float*)p;          p += NC_ * 4;
    p = (char*)(((size_t)p + 255) & ~(size_t)255);

    const size_t xcnt = (size_t)LN * LD;
    const size_t wcnt = (size_t)LI * LD;
    unsigned short* xh = (unsigned short*)p;
    unsigned short* wh = xh + xcnt;
    unsigned short* zk = wh + wcnt;
    char* big_end = (char*)(zk + (size_t)LN * LI);
    // dTb (bf16, 32 MB) overlays xh|wh (40 MB) — both dead after k_gemm_z.
    unsigned short* dTb = (unsigned short*)p;

    if ((size_t)(big_end - (char*)d_ws) > ws_size) return;   // ws too small

    k_cvt2<<<2560, 256, 0, stream>>>(x, gate, layer_idx, xh, wh);
    k_gemm_z<<<dim3(LI / 128, LN / 128), 256, 0, stream>>>(xh, wh, zk);

    hipMemsetAsync(ghist, 0, (size_t)LI * 4, stream);
    k_select<<<LN, 256, 0, stream>>>(zk, band, bandcnt, ghist);
    k_scan<<<1, 256, 0, stream>>>(ghist, offs, cursor);
    k_scatter<<<LN, 256, 0, stream>>>(band, bandcnt, cursor, inv);
    k_pairT<<<LI + 4096, 256, 0, stream>>>(x, gate, up, down, layer_idx,
                                           ghist, offs, inv, gdot, udot, dTb);
    k_finaldown<<<LN, 256, 0, stream>>>(band, bandcnt, gdot, udot, dTb, out);
}

// Round 10
// 304.806 us; speedup vs baseline: 1.4185x; 1.0303x over previous
//
#include <hip/hip_runtime.h>
#include <math.h>

constexpr int LI = 8192;   // I (intermediate)
constexpr int LD = 2048;   // D (hidden)
constexpr int LN = 2048;   // N (tokens)
constexpr int LK = 32;     // top_k
constexpr int CAP = 192;   // candidate band cap per row

typedef short short8 __attribute__((ext_vector_type(8)));
typedef unsigned short ushort8 __attribute__((ext_vector_type(8)));
typedef float f32x4 __attribute__((ext_vector_type(4)));
typedef const __attribute__((address_space(1))) void* gas1_t;
typedef __attribute__((address_space(3))) void* las3_t;

__device__ __forceinline__ void gload16(const void* g, void* l) {
    __builtin_amdgcn_global_load_lds((gas1_t)g, (las3_t)l, 16, 0, 0);
}
__device__ __forceinline__ unsigned short f2bf_rne(float f) {
    unsigned u = __float_as_uint(f);
    return (unsigned short)((u + 0x7fffu + ((u >> 16) & 1u)) >> 16);
}

// ---- fused fp32->bf16 convert: blocks [0,512) = x, [512,2560) = gate[l],
//      block 2560 zeroes ghist. 8 floats/thread, 16B ushort8 stores.
__global__ __launch_bounds__(256) void k_cvt2(
    const float* __restrict__ x, const float* __restrict__ gate,
    const int* __restrict__ layer_idx,
    unsigned short* __restrict__ xh, unsigned short* __restrict__ wh,
    int* __restrict__ ghist)
{
    if (blockIdx.x >= 2560) {          // ghist zero (replaces hipMemsetAsync)
        int t = threadIdx.x;
        #pragma unroll
        for (int b = 0; b < 32; ++b) ghist[t * 32 + b] = 0;
        return;
    }
    const float* src; unsigned short* dst; int n8, bid, nb;
    if (blockIdx.x < 512) {
        src = x; dst = xh; n8 = (LN * LD) / 8; bid = blockIdx.x; nb = 512;
    } else {
        src = gate + (size_t)layer_idx[0] * LI * LD; dst = wh;
        n8 = (LI * LD) / 8; bid = blockIdx.x - 512; nb = 2048;
    }
    int i = bid * 256 + threadIdx.x;
    int stride = nb * 256;
    for (; i < n8; i += stride) {
        float4 v0 = ((const float4*)src)[2 * i];
        float4 v1 = ((const float4*)src)[2 * i + 1];
        ushort8 h;
        h[0] = f2bf_rne(v0.x); h[1] = f2bf_rne(v0.y);
        h[2] = f2bf_rne(v0.z); h[3] = f2bf_rne(v0.w);
        h[4] = f2bf_rne(v1.x); h[5] = f2bf_rne(v1.y);
        h[6] = f2bf_rne(v1.z); h[7] = f2bf_rne(v1.w);
        ((ushort8*)dst)[i] = h;
    }
}

// ---- zk = bf16(|silu(x @ gw^T)|) via bf16 MFMA, 128x128 tile, BK=64.
// Verified structure (rounds 4-9). Only change: bijective XCD block swizzle
// (nwg=1024, cpx=128) for L2 x-panel locality. Per-block math identical.
__global__ __launch_bounds__(256) void k_gemm_z(
    const unsigned short* __restrict__ xh, const unsigned short* __restrict__ wh,
    unsigned short* __restrict__ zk)
{
    __shared__ short lds[16384];   // Ah|Bh, each [128][64] bf16 = 16KB
    short* Ah = lds;
    short* Bh = lds + 8192;

    const int tid = threadIdx.x;
    const int w = tid >> 6, lane = tid & 63;
    // XCD-aware bijective swizzle: flat in dispatch order, 8 XCDs, 128 wg each.
    const int flat = blockIdx.y * gridDim.x + blockIdx.x;   // 0..1023
    const int swz  = (flat & 7) * 128 + (flat >> 3);        // bijective
    const int bn = (swz >> 6) * 128;   // token rows   (16 panels)
    const int bi = (swz & 63) * 128;   // neuron rows  (64 panels)

    const int srow   = w * 32 + (lane >> 3);
    const int schunk = (lane & 7) ^ ((lane >> 3) & 7);
    const unsigned short* xbh = xh + (size_t)(bn + srow) * LD + schunk * 8;
    const unsigned short* wbh = wh + (size_t)(bi + srow) * LD + schunk * 8;

    f32x4 acc[4][4];
    #pragma unroll
    for (int m = 0; m < 4; ++m)
        #pragma unroll
        for (int n = 0; n < 4; ++n) acc[m][n] = (f32x4){0.f, 0.f, 0.f, 0.f};

    const int wm = (w >> 1) * 64, wn = (w & 1) * 64;

    #define STAGE(k0)                                                          \
        {                                                                      \
            _Pragma("unroll")                                                  \
            for (int t = 0; t < 4; ++t) {                                      \
                int ldo = (w * 32 + t * 8) * 64;                               \
                size_t go = (size_t)t * 8 * LD + (k0);                         \
                gload16(xbh + go, Ah + ldo);                                   \
                gload16(wbh + go, Bh + ldo);                                   \
            }                                                                  \
        }

    STAGE(0);
    __syncthreads();
    for (int k0 = 0;;) {
        #pragma unroll
        for (int ks = 0; ks < 2; ++ks) {
            short8 a_h[4], b_h[4];
            #pragma unroll
            for (int m = 0; m < 4; ++m) {
                int lr = wm + m * 16 + (lane & 15);
                int lc = ks * 4 + (lane >> 4);
                a_h[m] = *(const short8*)(Ah + lr * 64 + ((lc ^ (lr & 7)) << 3));
            }
            #pragma unroll
            for (int n = 0; n < 4; ++n) {
                int lr = wn + n * 16 + (lane & 15);
                int lc = ks * 4 + (lane >> 4);
                b_h[n] = *(const short8*)(Bh + lr * 64 + ((lc ^ (lr & 7)) << 3));
            }
            #pragma unroll
            for (int m = 0; m < 4; ++m)
                #pragma unroll
                for (int n = 0; n < 4; ++n)
                    acc[m][n] = __builtin_amdgcn_mfma_f32_16x16x32_bf16(a_h[m], b_h[n], acc[m][n], 0, 0, 0);
        }
        k0 += 64;
        if (k0 >= LD) break;
        __syncthreads();
        STAGE(k0);
        __syncthreads();
    }

    #pragma unroll
    for (int m = 0; m < 4; ++m) {
        int rb = bn + wm + m * 16 + (lane >> 4) * 4;
        #pragma unroll
        for (int n = 0; n < 4; ++n) {
            int cb = bi + wn + n * 16 + (lane & 15);
            #pragma unroll
            for (int r = 0; r < 4; ++r) {
                float zv = acc[m][n][r];
                float g = zv / (1.f + expf(-zv));
                zk[(size_t)(rb + r) * LI + cb] = f2bf_rne(fabsf(g));
            }
        }
    }
    #undef STAGE
}

// ---- band selection: bf16-ulp histogram (1024 bins over [0.25,64)),
// threshold bin covering rank-32, band = keys >= binfloor - MARGIN.
// Keys held in registers; sub-0.25 keys skip the histogram atomic
// (bit-identical result: thrbin=0 fallback path is unchanged).
__global__ __launch_bounds__(256) void k_select(
    const unsigned short* __restrict__ zk, int* __restrict__ band,
    int* __restrict__ bandcnt, int* __restrict__ ghist)
{
    __shared__ int hist[1024];   // 4 KB
    __shared__ int sums[256];
    __shared__ int base_s;
    __shared__ int thrbin_s;

    const int row = blockIdx.x;
    const int tid = threadIdx.x;
    const int lane = tid & 63;
    const unsigned short* __restrict__ z = zk + (size_t)row * LI;

    if (tid == 0) { thrbin_s = 0; base_s = 0; }
    for (int i = tid; i < 1024; i += 256) hist[i] = 0;
    __syncthreads();

    // phase 1: vectorized load (keys stay in registers) + histogram (keys>=0.25)
    ushort8 kv[4];
    #pragma unroll
    for (int c = 0; c < 4; ++c) {
        kv[c] = *(const ushort8*)(z + c * 2048 + tid * 8);
        #pragma unroll
        for (int j = 0; j < 8; ++j) {
            int b = (int)kv[c][j] - 0x3E80;            // bf16 bits of 0.25
            if (b > 0) {
                b = b > 1023 ? 1023 : b;
                atomicAdd(&hist[b], 1);
            }
        }
    }
    __syncthreads();

    int own = 0;
    #pragma unroll
    for (int b = 0; b < 4; ++b) own += hist[tid * 4 + b];
    sums[tid] = own;
    __syncthreads();
    for (int st = 1; st < 256; st <<= 1) {   // suffix inclusive scan
        int v = (tid + st < 256) ? sums[tid + st] : 0;
        __syncthreads();
        sums[tid] += v;
        __syncthreads();
    }
    int after = (tid < 255) ? sums[tid + 1] : 0;
    if (after < LK && after + own >= LK) {   // unique crossing thread
        int cum = after;
        for (int b = 3; b >= 0; --b) {
            cum += hist[tid * 4 + b];
            if (cum >= LK) { thrbin_s = tid * 4 + b; break; }
        }
    }
    __syncthreads();
    const float bandlo =
        __uint_as_float((unsigned)(0x3E80 + thrbin_s) << 16) - 0.06f;

    // phase 2: band compaction from registers (order irrelevant; re-sorted later)
    #pragma unroll
    for (int c = 0; c < 4; ++c) {
        unsigned flags = 0;
        #pragma unroll
        for (int j = 0; j < 8; ++j) {
            float kf = __uint_as_float(((unsigned)kv[c][j]) << 16);
            if (kf >= bandlo) flags |= (1u << j);
        }
        int cnt = __popc(flags);
        int pre = cnt;                        // wave inclusive scan
        #pragma unroll
        for (int o = 1; o < 64; o <<= 1) {
            int v = __shfl_up(pre, o);
            if (lane >= o) pre += v;
        }
        int wtotal = __shfl(pre, 63);
        int excl = pre - cnt;
        int wbase = 0;
        if (lane == 63 && wtotal) wbase = atomicAdd(&base_s, wtotal);
        wbase = __shfl(wbase, 63);
        int pos = wbase + excl;
        while (flags) {
            int j = __ffs(flags) - 1;
            flags &= flags - 1;
            if (pos < CAP) {
                int gi = c * 2048 + tid * 8 + j;
                band[row * CAP + pos] = gi;
                atomicAdd(&ghist[gi], 1);
            }
            ++pos;
        }
    }
    __syncthreads();
    if (tid == 0) bandcnt[row] = base_s < CAP ? base_s : CAP;
}

// ---- exclusive prefix-sum of ghist[8192] -> offs, cursor (single block)
__global__ __launch_bounds__(256) void k_scan(
    const int* __restrict__ ghist, int* __restrict__ offs, int* __restrict__ cursor)
{
    __shared__ int sums[256];
    const int tid = threadIdx.x;
    int loc[32];
    int s = 0;
    #pragma unroll
    for (int b = 0; b < 32; ++b) { loc[b] = s; s += ghist[tid * 32 + b]; }
    sums[tid] = s;
    __syncthreads();
    for (int st = 1; st < 256; st <<= 1) {
        int v = (tid >= st) ? sums[tid - st] : 0;
        __syncthreads();
        sums[tid] += v;
        __syncthreads();
    }
    int base = (tid > 0) ? sums[tid - 1] : 0;
    #pragma unroll
    for (int b = 0; b < 32; ++b) {
        int o = base + loc[b];
        offs[tid * 32 + b]   = o;
        cursor[tid * 32 + b] = o;
    }
}

// ---- scatter band entries into neuron-major inverted list
__global__ __launch_bounds__(256) void k_scatter(
    const int* __restrict__ band, const int* __restrict__ bandcnt,
    int* __restrict__ cursor, int* __restrict__ inv)
{
    const int row = blockIdx.x;
    const int tid = threadIdx.x;
    int cnt = bandcnt[row];
    if (tid < cnt) {
        int j = band[row * CAP + tid] & (LI - 1);
        int p = atomicAdd(&cursor[j], 1);
        inv[p] = (row << 8) | tid;
    }
}

// ---- FUSED: blocks [0,LI) = neuron-major exact rescore (pair);
//             blocks [LI, LI+4096) = transpose down[D,I] -> dT bf16 [I,D].
__global__ __launch_bounds__(256) void k_pairT(
    const float* __restrict__ x, const float* __restrict__ gate,
    const float* __restrict__ up, const float* __restrict__ down,
    const int* __restrict__ layer_idx,
    const int* __restrict__ ghist, const int* __restrict__ offs,
    const int* __restrict__ inv,
    float* __restrict__ gdot, float* __restrict__ udot,
    unsigned short* __restrict__ dTb)
{
    __shared__ float smem[4160];   // pair: gs|us (16 KB); transpose: 64x65 tile
    const int tid = threadIdx.x;

    if (blockIdx.x < LI) {
        // ---------------- pair body ----------------
        float* gs = smem;
        float* us = smem + LD;
        const int j = blockIdx.x;
        const int lane = tid & 63, w = tid >> 6;
        const int nj = ghist[j];
        if (nj == 0) return;
        const float* __restrict__ gr = gate + (size_t)layer_idx[0] * LI * LD + (size_t)j * LD;
        const float* __restrict__ ur = up   + (size_t)layer_idx[0] * LI * LD + (size_t)j * LD;
        for (int i = tid * 4; i < LD; i += 1024) {
            *(float4*)&gs[i] = *(const float4*)(gr + i);
            *(float4*)&us[i] = *(const float4*)(ur + i);
        }
        __syncthreads();
        const int base = offs[j];
        for (int e = w; e < nj; e += 4) {
            int packed = inv[base + e];
            int row = packed >> 8, slot = packed & 255;
            const float* __restrict__ xr = x + (size_t)row * LD;
            float gd0 = 0.f, gd1 = 0.f, ud0 = 0.f, ud1 = 0.f;
            #pragma unroll
            for (int it = 0; it < 8; it += 2) {
                int i0 = lane * 4 + it * 256;
                int i1 = i0 + 256;
                float4 xa = *(const float4*)(xr + i0);
                float4 xb = *(const float4*)(xr + i1);
                gd0 = fmaf(xa.x, gs[i0+0], gd0); gd0 = fmaf(xa.y, gs[i0+1], gd0);
                gd0 = fmaf(xa.z, gs[i0+2], gd0); gd0 = fmaf(xa.w, gs[i0+3], gd0);
                ud0 = fmaf(xa.x, us[i0+0], ud0); ud0 = fmaf(xa.y, us[i0+1], ud0);
                ud0 = fmaf(xa.z, us[i0+2], ud0); ud0 = fmaf(xa.w, us[i0+3], ud0);
                gd1 = fmaf(xb.x, gs[i1+0], gd1); gd1 = fmaf(xb.y, gs[i1+1], gd1);
                gd1 = fmaf(xb.z, gs[i1+2], gd1); gd1 = fmaf(xb.w, gs[i1+3], gd1);
                ud1 = fmaf(xb.x, us[i1+0], ud1); ud1 = fmaf(xb.y, us[i1+1], ud1);
                ud1 = fmaf(xb.z, us[i1+2], ud1); ud1 = fmaf(xb.w, us[i1+3], ud1);
            }
            float gd = gd0 + gd1, ud = ud0 + ud1;
            #pragma unroll
            for (int o = 32; o; o >>= 1) {
                gd += __shfl_down(gd, o);
                ud += __shfl_down(ud, o);
            }
            if (lane == 0) {
                gdot[(size_t)row * CAP + slot] = gd;
                udot[(size_t)row * CAP + slot] = ud;
            }
        }
    } else {
        // ---------------- transpose body: 64x64 tiles, bf16 out -------
        float (*t)[65] = (float(*)[65])smem;
        const float* __restrict__ dw = down + (size_t)layer_idx[0] * LD * LI;
        const int bid2 = blockIdx.x - LI;
        const int bi = (bid2 & 127) * 64;   // I
        const int bd = (bid2 >> 7) * 64;    // D
        const int tx = tid & 63, ty = tid >> 6;
        #pragma unroll
        for (int it = 0; it < 16; ++it) {
            int r = ty + it * 4;
            t[r][tx] = dw[(size_t)(bd + r) * LI + bi + tx];
        }
        __syncthreads();
        #pragma unroll
        for (int it = 0; it < 16; ++it) {
            int rr = ty + it * 4;
            dTb[(size_t)(bi + rr) * LD + bd + tx] = f2bf_rne(t[tx][rr]);
        }
    }
}

// ---- FUSED final: per-row exact top-32 among band (desc exact key, asc idx),
// gu = silu*u, then down-gather: out[n,:] = sum_k gu_k * dTb[idx_k, :]
__global__ __launch_bounds__(256) void k_finaldown(
    const int* __restrict__ band, const int* __restrict__ bandcnt,
    const float* __restrict__ gdot, const float* __restrict__ udot,
    const unsigned short* __restrict__ dTb, float* __restrict__ out)
{
    __shared__ float ckey[CAP];
    __shared__ float cgu[CAP];
    __shared__ int   cidx[CAP];
    __shared__ int   js[LK];
    __shared__ float wgt[LK];
    const int row = blockIdx.x;
    const int tid = threadIdx.x;
    const int lane = tid & 63;
    const int cnt = bandcnt[row];
    if (tid < CAP) { ckey[tid] = -1.f; cgu[tid] = 0.f; cidx[tid] = 0x7fffffff; }
    __syncthreads();
    if (tid < cnt) {
        float gd = gdot[(size_t)row * CAP + tid];
        float g = gd / (1.f + expf(-gd));
        ckey[tid] = fabsf(g);
        cgu[tid]  = g * udot[(size_t)row * CAP + tid];
        cidx[tid] = band[row * CAP + tid];
    }
    __syncthreads();
    if (tid < 64) {
        float k1 = ckey[lane], k2 = ckey[lane + 64], k3 = ckey[lane + 128];
        int   i1 = cidx[lane], i2 = cidx[lane + 64], i3 = cidx[lane + 128];
        int   p1 = lane, p2 = lane + 64, p3 = lane + 128;
        for (int slot = 0; slot < LK; ++slot) {
            float bk = k1; int bi_ = i1, bp = p1;
            if (k2 > bk || (k2 == bk && i2 < bi_)) { bk = k2; bi_ = i2; bp = p2; }
            if (k3 > bk || (k3 == bk && i3 < bi_)) { bk = k3; bi_ = i3; bp = p3; }
            #pragma unroll
            for (int o = 1; o < 64; o <<= 1) {
                float ok = __shfl_xor(bk, o);
                int  oi = __shfl_xor(bi_, o);
                int  op = __shfl_xor(bp, o);
                if (ok > bk || (ok == bk && oi < bi_)) { bk = ok; bi_ = oi; bp = op; }
            }
            if (lane == 0) {
                js[slot]  = bi_ & (LI - 1);
                wgt[slot] = cgu[bp < CAP ? bp : 0];
            }
            if (p1 == bp) { k1 = -1.f; i1 = 0x7fffffff; }
            if (p2 == bp) { k2 = -1.f; i2 = 0x7fffffff; }
            if (p3 == bp) { k3 = -1.f; i3 = 0x7fffffff; }
        }
    }
    __syncthreads();

    // down-gather (bf16 rows)
    float a[8] = {0.f,0.f,0.f,0.f,0.f,0.f,0.f,0.f};
    #pragma unroll 4
    for (int k = 0; k < LK; ++k) {
        const ushort8 v = *(const ushort8*)(dTb + (size_t)js[k] * LD + tid * 8);
        float wv = wgt[k];
        #pragma unroll
        for (int e = 0; e < 8; ++e)
            a[e] = fmaf(wv, __uint_as_float(((unsigned)v[e]) << 16), a[e]);
    }
    float* o = out + (size_t)row * LD + tid * 8;
    float4 o0 = {a[0], a[1], a[2], a[3]};
    float4 o1 = {a[4], a[5], a[6], a[7]};
    *(float4*)o = o0;
    *(float4*)(o + 4) = o1;
}

extern "C" void kernel_launch(void* const* d_in, const int* in_sizes, int n_in,
                              void* d_out, int out_size, void* d_ws, size_t ws_size,
                              hipStream_t stream)
{
    const float* x      = (const float*)d_in[0];
    const float* gate   = (const float*)d_in[1];
    const float* up     = (const float*)d_in[2];
    const float* down   = (const float*)d_in[3];
    const int* layer_idx = (const int*)d_in[4];
    float* out = (float*)d_out;

    // ---- ws layout: small region, then big region (xh|wh|zk, reused for dTb)
    const size_t NK = (size_t)LN * LK;
    const size_t NC_ = (size_t)LN * CAP;
    char* p = (char*)d_ws;
    p += NK * 4;                          // (reserved, unused)
    p += NK * 4;                          // (reserved, unused)
    int*   band    = (int*)p;            p += NC_ * 4;
    int*   bandcnt = (int*)p;            p += (size_t)LN * 4;
    int*   ghist   = (int*)p;            p += (size_t)LI * 4;
    int*   offs    = (int*)p;            p += (size_t)LI * 4;
    int*   cursor  = (int*)p;            p += (size_t)LI * 4;
    int*   inv     = (int*)p;            p += NC_ * 4;
    float* gdot    = (float*)p;          p += NC_ * 4;
    float* udot    = (float*)p;          p += NC_ * 4;
    p = (char*)(((size_t)p + 255) & ~(size_t)255);

    const size_t xcnt = (size_t)LN * LD;
    const size_t wcnt = (size_t)LI * LD;
    unsigned short* xh = (unsigned short*)p;
    unsigned short* wh = xh + xcnt;
    unsigned short* zk = wh + wcnt;
    char* big_end = (char*)(zk + (size_t)LN * LI);
    // dTb (bf16, 32 MB) overlays xh|wh (40 MB) — both dead after k_gemm_z.
    unsigned short* dTb = (unsigned short*)p;

    if ((size_t)(big_end - (char*)d_ws) > ws_size) return;   // ws too small

    k_cvt2<<<2561, 256, 0, stream>>>(x, gate, layer_idx, xh, wh, ghist);
    k_gemm_z<<<dim3(64, 16), 256, 0, stream>>>(xh, wh, zk);

    k_select<<<LN, 256, 0, stream>>>(zk, band, bandcnt, ghist);
    k_scan<<<1, 256, 0, stream>>>(ghist, offs, cursor);
    k_scatter<<<LN, 256, 0, stream>>>(band, bandcnt, cursor, inv);
    k_pairT<<<LI + 4096, 256, 0, stream>>>(x, gate, up, down, layer_idx,
                                           ghist, offs, inv, gdot, udot, dTb);
    k_finaldown<<<LN, 256, 0, stream>>>(band, bandcnt, gdot, udot, dTb, out);
}